// Round 5
// baseline (249.509 us; speedup 1.0000x reference)
//
#include <hip/hip_runtime.h>

// ---------------------------------------------------------------------------
// LoRA_Attention: fold LoRA into weights; bf16 MFMA GEMMs (global_load_lds
// DMA staging); split-K flash attention with S^T orientation, key-split
// waves, cross-iteration register prefetch, XCD-swizzled grid; rel-pos bias
// via 48x48x64 MFMA GEMMs; exp2 softmax, no-max (scores bounded).
// ---------------------------------------------------------------------------

#define DIM   768
#define HEADS 12
#define HD    64
#define NTOK  2304
#define RANK  8
#define GRD   48
#define CHUNKS 4
#define LOG2E 1.44269504088896f

typedef __attribute__((ext_vector_type(8))) short bf16x8;
typedef __attribute__((ext_vector_type(4))) float f32x4;
typedef unsigned short ushort_t;

__device__ __forceinline__ unsigned short f2bf(float x) {
    union { float f; unsigned u; } v; v.f = x;
    unsigned r = v.u + 0x7fffu + ((v.u >> 16) & 1u);
    return (unsigned short)(r >> 16);
}

__device__ __forceinline__ void gload_lds16(const ushort_t* g, ushort_t* l) {
    __builtin_amdgcn_global_load_lds(
        (const __attribute__((address_space(1))) unsigned int*)g,
        (__attribute__((address_space(3))) unsigned int*)l, 16, 0, 0);
}

// ---------------------------------------------------------------------------
// Stage 0: convert x -> bf16; blocks >= 1728 convert rel_pos tables -> bf16.
// ---------------------------------------------------------------------------
__global__ __launch_bounds__(256) void k_convert_x(
    const float* __restrict__ x, ushort_t* __restrict__ xb,
    const float* __restrict__ rph, const float* __restrict__ rpw,
    ushort_t* __restrict__ rphb, ushort_t* __restrict__ rpwb) {
    if (blockIdx.x < 1728) {
        int idx = (blockIdx.x * 256 + threadIdx.x) * 4;
        float4 v = *(const float4*)(x + idx);
        ushort4 o = make_ushort4(f2bf(v.x), f2bf(v.y), f2bf(v.z), f2bf(v.w));
        *(ushort4*)(xb + idx) = o;
    } else {
        int e = ((blockIdx.x - 1728) * 256 + threadIdx.x) * 4;
        const int TSZ = (2 * GRD - 1) * HD;   // 6080
        if (e < TSZ) {
            float4 v = *(const float4*)(rph + e);
            ushort4 o = make_ushort4(f2bf(v.x), f2bf(v.y), f2bf(v.z), f2bf(v.w));
            *(ushort4*)(rphb + e) = o;
        } else if (e < 2 * TSZ) {
            float4 v = *(const float4*)(rpw + e - TSZ);
            ushort4 o = make_ushort4(f2bf(v.x), f2bf(v.y), f2bf(v.z), f2bf(v.w));
            *(ushort4*)(rpwb + e - TSZ) = o;
        }
    }
}

// ---------------------------------------------------------------------------
__global__ __launch_bounds__(256) void k_fold(
    const float* __restrict__ Wq, const float* __restrict__ Wk,
    const float* __restrict__ Wv, const float* __restrict__ Wp,
    const float* __restrict__ Aq, const float* __restrict__ Bq,
    const float* __restrict__ Ak, const float* __restrict__ Bk,
    const float* __restrict__ Av, const float* __restrict__ Bv,
    ushort_t* __restrict__ WT) {
    int kb = blockIdx.x * 32;
    int nb = blockIdx.y * 32;
    int qkv = nb / DIM;
    int nmod = nb % DIM;
    const float* W = (qkv == 0) ? Wq : (qkv == 1) ? Wk : (qkv == 2) ? Wv : Wp;
    const float* A = (qkv == 0) ? Aq : (qkv == 1) ? Ak : Av;
    const float* B = (qkv == 0) ? Bq : (qkv == 1) ? Bk : Bv;

    __shared__ float T[32][33];
    for (int i = threadIdx.x; i < 1024; i += 256) {
        int kl = i / 32, nl = i % 32;
        float v = W[(kb + kl) * DIM + nmod + nl];
        if (qkv < 3) {
            #pragma unroll
            for (int r = 0; r < RANK; r++)
                v += A[(kb + kl) * RANK + r] * B[r * DIM + nmod + nl];
        }
        T[kl][nl] = v;
    }
    __syncthreads();
    for (int i = threadIdx.x; i < 1024; i += 256) {
        int nl = i / 32, kl = i % 32;
        WT[(size_t)(nb + nl) * DIM + kb + kl] = f2bf(T[kl][nl]);
    }
}

// ---------------------------------------------------------------------------
// QKV GEMM: 128x128 tile, BK=32, global_load_lds width-16 DMA staging,
// unpadded [row][32] LDS (64B rows -> 2-way bank = free). 2x2 waves of 64x64.
// ---------------------------------------------------------------------------
__global__ __launch_bounds__(256) void k_gemm_qkv(
    const ushort_t* __restrict__ xb, const ushort_t* __restrict__ WT,
    const float* __restrict__ bq, const float* __restrict__ bk,
    const float* __restrict__ bv,
    ushort_t* __restrict__ Qb, ushort_t* __restrict__ Kb,
    ushort_t* __restrict__ Vtb) {
    __shared__ __align__(16) ushort_t As[128 * 32];
    __shared__ __align__(16) ushort_t Bs[128 * 32];
    int tid = threadIdx.x;
    int wave = tid >> 6, lane = tid & 63, quad = lane >> 4, l16 = lane & 15;
    int wx = wave & 1, wy = wave >> 1;
    int nb = blockIdx.x * 128, mb = blockIdx.y * 128;

    f32x4 zero = {0.f, 0.f, 0.f, 0.f};
    f32x4 acc[4][4];
    #pragma unroll
    for (int i = 0; i < 4; i++)
        #pragma unroll
        for (int j = 0; j < 4; j++) acc[i][j] = zero;

    int rl = lane >> 2;            // 0..15
    int cl = (lane & 3) * 8;       // element col within 32
    const ushort_t* gA = xb + (size_t)(mb + wave * 32 + rl) * DIM + cl;
    const ushort_t* gB = WT + (size_t)(nb + wave * 32 + rl) * DIM + cl;
    ushort_t* lA = &As[(wave * 32) * 32];   // HW adds lane*16B
    ushort_t* lB = &Bs[(wave * 32) * 32];

    for (int k0 = 0; k0 < DIM; k0 += 32) {
        __syncthreads();
        gload_lds16(gA + k0,            lA);
        gload_lds16(gA + k0 + 16 * DIM, lA + 16 * 32);
        gload_lds16(gB + k0,            lB);
        gload_lds16(gB + k0 + 16 * DIM, lB + 16 * 32);
        __syncthreads();
        bf16x8 af[4], bf[4];
        #pragma unroll
        for (int i = 0; i < 4; i++)
            af[i] = *(const bf16x8*)&As[(wy * 64 + i * 16 + l16) * 32 + quad * 8];
        #pragma unroll
        for (int j = 0; j < 4; j++)
            bf[j] = *(const bf16x8*)&Bs[(wx * 64 + j * 16 + l16) * 32 + quad * 8];
        #pragma unroll
        for (int i = 0; i < 4; i++)
            #pragma unroll
            for (int j = 0; j < 4; j++)
                acc[i][j] = __builtin_amdgcn_mfma_f32_16x16x32_bf16(af[i], bf[j], acc[i][j], 0, 0, 0);
    }

    #pragma unroll
    for (int j = 0; j < 4; j++) {
        int col = nb + wx * 64 + j * 16 + l16;
        int qkv = col / DIM, rem = col % DIM;
        int hh = rem >> 6, cc = rem & 63;
        const float* bias = (qkv == 0) ? bq : (qkv == 1) ? bk : bv;
        float bval = bias[rem];
        #pragma unroll
        for (int i = 0; i < 4; i++) {
            #pragma unroll
            for (int r = 0; r < 4; r++) {
                int row = mb + wy * 64 + i * 16 + quad * 4 + r;
                unsigned short o = f2bf(acc[i][j][r] + bval);
                if (qkv == 0)      Qb[(size_t)(hh * NTOK + row) * HD + cc] = o;
                else if (qkv == 1) Kb[(size_t)(hh * NTOK + row) * HD + cc] = o;
                else               Vtb[(size_t)(hh * HD + cc) * NTOK + row] = o;
            }
        }
    }
}

// ---------------------------------------------------------------------------
// Rel-pos bias via MFMA (outputs pre-scaled by log2 e).
// ---------------------------------------------------------------------------
__global__ __launch_bounds__(256) void k_relmm(
    const ushort_t* __restrict__ Qb, const ushort_t* __restrict__ rphb,
    const ushort_t* __restrict__ rpwb, float* __restrict__ relH,
    float* __restrict__ relW) {
    int id = blockIdx.x * 4 + (threadIdx.x >> 6);
    int lane = threadIdx.x & 63, quad = lane >> 4, l16 = lane & 15;
    bool isW = id >= 576;
    int t = isW ? id - 576 : id;
    int h = t / GRD, g = t % GRD;
    const ushort_t* tab = isW ? rpwb : rphb;
    float* outp = isW ? relW : relH;

    f32x4 zero = {0.f, 0.f, 0.f, 0.f};
    f32x4 acc[3][3];
    #pragma unroll
    for (int i = 0; i < 3; i++)
        #pragma unroll
        for (int j = 0; j < 3; j++) acc[i][j] = zero;

    bf16x8 bfr[3][2];
    #pragma unroll
    for (int ct = 0; ct < 3; ct++) {
        int trow = g + 47 - (ct * 16 + l16);
        bfr[ct][0] = *(const bf16x8*)&tab[(size_t)trow * HD + quad * 8];
        bfr[ct][1] = *(const bf16x8*)&tab[(size_t)trow * HD + 32 + quad * 8];
    }
    #pragma unroll
    for (int ms = 0; ms < 3; ms++) {
        int m = ms * 16 + l16;
        int n = isW ? m * GRD + g : g * GRD + m;
        bf16x8 a0 = *(const bf16x8*)&Qb[(size_t)(h * NTOK + n) * HD + quad * 8];
        bf16x8 a1 = *(const bf16x8*)&Qb[(size_t)(h * NTOK + n) * HD + 32 + quad * 8];
        #pragma unroll
        for (int ct = 0; ct < 3; ct++) {
            acc[ms][ct] = __builtin_amdgcn_mfma_f32_16x16x32_bf16(a0, bfr[ct][0], acc[ms][ct], 0, 0, 0);
            acc[ms][ct] = __builtin_amdgcn_mfma_f32_16x16x32_bf16(a1, bfr[ct][1], acc[ms][ct], 0, 0, 0);
        }
    }
    #pragma unroll
    for (int ms = 0; ms < 3; ms++) {
        #pragma unroll
        for (int ct = 0; ct < 3; ct++) {
            #pragma unroll
            for (int r = 0; r < 4; r++) {
                int m = ms * 16 + quad * 4 + r;
                int n = isW ? m * GRD + g : g * GRD + m;
                int col = ct * 16 + l16;
                outp[(size_t)(h * NTOK + n) * GRD + col] = acc[ms][ct][r] * LOG2E;
            }
        }
    }
}

// ---------------------------------------------------------------------------
// Flash attention, split-K, S^T orientation, key-split waves.
// Grid = (h*4+chunk, qt) so the 36 q-blocks sharing a K/V tile have equal
// blockid mod 8 -> same XCD L2. Cross-iteration prefetch: next iter's K
// A-frags and this iter's V B-frags issue at iter top, hidden behind
// MFMA+softmax. P packed to per-wave LDS via v_perm (RTZ bf16; bias cancels
// in the sum(pV)/sum(p) ratio). Parallel 4-round cross-wave O reduction.
// ---------------------------------------------------------------------------
__global__ __launch_bounds__(256) void k_attn(
    const ushort_t* __restrict__ Qb, const ushort_t* __restrict__ Kb,
    const ushort_t* __restrict__ Vtb, const float* __restrict__ relH,
    const float* __restrict__ relW, float* __restrict__ Opart,
    float* __restrict__ Lpart) {
    int h = blockIdx.x >> 2, chunk = blockIdx.x & 3, qt = blockIdx.y;
    int tid = threadIdx.x;
    int wave = tid >> 6, lane = tid & 63, quad = lane >> 4, l16 = lane & 15;
    int qbase = qt * 64;
    int kbase = chunk * 576;

    __shared__ __align__(16) ushort_t Ps[4][64 * 40];  // per-wave P [qrow][32key]; reused as f32 buf
    __shared__ __align__(16) float rwsf[64 * 52];      // fp32 relW [qrow][48], stride 52
    __shared__ float rhs[64 * 13];                     // fp32 relH [qrow][12], stride 13
    __shared__ float Lred[4][64];

    // stage rel terms (both pre-scaled by log2e in k_relmm)
    for (int i = tid; i < 64 * 48; i += 256) {
        int r = i / 48, c = i % 48;
        rwsf[r * 52 + c] = relW[(size_t)(h * NTOK + qbase + r) * GRD + c];
    }
    for (int i = tid; i < 64 * 12; i += 256) {
        int r = i / 12, c = i % 12;
        rhs[r * 13 + c] = relH[(size_t)(h * NTOK + qbase + r) * GRD + chunk * 12 + c];
    }

    // Q B-fragments: qf[qs][half]  (B[k=c][n=qrow], n=l16)
    bf16x8 qf[4][2];
    #pragma unroll
    for (int qs = 0; qs < 4; qs++) {
        int qrow = qbase + qs * 16 + l16;
        qf[qs][0] = *(const bf16x8*)&Qb[(size_t)(h * NTOK + qrow) * HD + quad * 8];
        qf[qs][1] = *(const bf16x8*)&Qb[(size_t)(h * NTOK + qrow) * HD + 32 + quad * 8];
    }

    float lacc[4] = {0.f, 0.f, 0.f, 0.f};
    f32x4 zero = {0.f, 0.f, 0.f, 0.f};
    f32x4 oacc[4][4];
    #pragma unroll
    for (int qs = 0; qs < 4; qs++)
        #pragma unroll
        for (int cs = 0; cs < 4; cs++) oacc[qs][cs] = zero;

    const float scale2 = 0.125f * LOG2E;
    __syncthreads();   // rel staging visible; no more barriers until epilogue

    // K A-frags for iter 0 (prefetched)
    bf16x8 ckf[4], nkf[4];
    {
        int keyw = kbase + wave * 32;
        const ushort_t* kp = Kb + (size_t)(h * NTOK + keyw + l16) * HD;
        ckf[0] = *(const bf16x8*)(kp + quad * 8);
        ckf[1] = *(const bf16x8*)(kp + 32 + quad * 8);
        ckf[2] = *(const bf16x8*)(kp + 16 * HD + quad * 8);
        ckf[3] = *(const bf16x8*)(kp + 16 * HD + 32 + quad * 8);
    }

    // 4 full iters x 128 keys (wave owns 32) + 1 tail iter x 64 keys (wave owns 16)
    #pragma unroll
    for (int it = 0; it < 5; ++it) {
        bool full = (it < 4);
        int keyw = kbase + it * 128 + wave * (full ? 32 : 16);

        // V B-frags for THIS iter — issued now, consumed ~400cyc later at PV
        bf16x8 vf[4];
        #pragma unroll
        for (int cs = 0; cs < 4; cs++)
            vf[cs] = *(const bf16x8*)&Vtb[(size_t)(h * HD + cs * 16 + l16) * NTOK + keyw + quad * 8];

        // K A-frags for NEXT iter — prefetch
        if (it < 4) {
            bool fn = (it + 1 < 4);
            int keywn = kbase + (it + 1) * 128 + wave * (fn ? 32 : 16);
            const ushort_t* kp = Kb + (size_t)(h * NTOK + keywn + l16) * HD;
            nkf[0] = *(const bf16x8*)(kp + quad * 8);
            nkf[1] = *(const bf16x8*)(kp + 32 + quad * 8);
            if (fn) {
                nkf[2] = *(const bf16x8*)(kp + 16 * HD + quad * 8);
                nkf[3] = *(const bf16x8*)(kp + 16 * HD + 32 + quad * 8);
            }
        }

        // per 16-key group: S^T MFMA -> softmax -> P pack/store
        int nks = full ? 2 : 1;
        #pragma unroll
        for (int ks = 0; ks < 2; ++ks) {
            if (ks >= nks) break;
            f32x4 st[4];
            #pragma unroll
            for (int qs = 0; qs < 4; qs++) {
                f32x4 z = zero;
                z = __builtin_amdgcn_mfma_f32_16x16x32_bf16(ckf[ks * 2], qf[qs][0], z, 0, 0, 0);
                z = __builtin_amdgcn_mfma_f32_16x16x32_bf16(ckf[ks * 2 + 1], qf[qs][1], z, 0, 0, 0);
                st[qs] = z;
            }
            int kb4 = keyw + ks * 16 + quad * 4;      // lane's first key
            int kh = kb4 / 48;
            int khl = kh - chunk * 12;
            int kw0 = kb4 - kh * 48;                  // multiple of 4
            #pragma unroll
            for (int qs = 0; qs < 4; qs++) {
                int row = qs * 16 + l16;
                float rh = rhs[row * 13 + khl];
                float4 rw = *(const float4*)&rwsf[row * 52 + kw0];
                float p0 = __builtin_amdgcn_exp2f(st[qs][0] * scale2 + rh + rw.x);
                float p1 = __builtin_amdgcn_exp2f(st[qs][1] * scale2 + rh + rw.y);
                float p2 = __builtin_amdgcn_exp2f(st[qs][2] * scale2 + rh + rw.z);
                float p3 = __builtin_amdgcn_exp2f(st[qs][3] * scale2 + rh + rw.w);
                lacc[qs] += (p0 + p1) + (p2 + p3);
                uint2 w;
                w.x = __builtin_amdgcn_perm(__float_as_uint(p1), __float_as_uint(p0), 0x07060302u);
                w.y = __builtin_amdgcn_perm(__float_as_uint(p3), __float_as_uint(p2), 0x07060302u);
                *(uint2*)&Ps[wave][row * 40 + ks * 16 + quad * 4] = w;
            }
        }
        if (!full) {
            uint2 zz; zz.x = 0u; zz.y = 0u;
            #pragma unroll
            for (int qs = 0; qs < 4; qs++)
                *(uint2*)&Ps[wave][(qs * 16 + l16) * 40 + 16 + quad * 4] = zz;
        }

        // PV: A[m=qrow][k=key32] b128 from own Ps, B=vf
        #pragma unroll
        for (int qs = 0; qs < 4; qs++) {
            bf16x8 pa = *(const bf16x8*)&Ps[wave][(qs * 16 + l16) * 40 + quad * 8];
            #pragma unroll
            for (int cs = 0; cs < 4; cs++)
                oacc[qs][cs] = __builtin_amdgcn_mfma_f32_16x16x32_bf16(pa, vf[cs], oacc[qs][cs], 0, 0, 0);
        }

        #pragma unroll
        for (int i = 0; i < 4; i++) ckf[i] = nkf[i];
    }

    // l: reduce across quads (keys split over quads within wave)
    #pragma unroll
    for (int qs = 0; qs < 4; qs++) {
        float l = lacc[qs];
        l += __shfl_xor(l, 16);
        l += __shfl_xor(l, 32);
        lacc[qs] = l;
    }
    if (quad == 0) {
        #pragma unroll
        for (int qs = 0; qs < 4; qs++) Lred[wave][qs * 16 + l16] = lacc[qs];
    }

    __syncthreads();   // all PV reads of Ps done, Lred written

    size_t obase = (size_t)(chunk * HEADS + h) * HD * NTOK;
    if (tid < 64) {
        float s = Lred[0][tid] + Lred[1][tid] + Lred[2][tid] + Lred[3][tid];
        Lpart[(size_t)(chunk * HEADS + h) * NTOK + qbase + tid] = s;
    }

    // cross-wave O reduction: 4 rounds over cs-quarters, all waves active.
    // buf = [writer][16 cols][68 rows] f32, reuses Ps (17.4 KB <= 20.5 KB).
    float* buf = (float*)&Ps[0][0];
    int rcol = tid >> 4, rseg = tid & 15;
    #pragma unroll
    for (int j = 0; j < 4; j++) {
        #pragma unroll
        for (int qs = 0; qs < 4; qs++)
            *(f32x4*)&buf[(wave * 16 + l16) * 68 + qs * 16 + quad * 4] = oacc[qs][j];
        __syncthreads();
        f32x4 s = *(const f32x4*)&buf[(0 * 16 + rcol) * 68 + rseg * 4];
        s += *(const f32x4*)&buf[(1 * 16 + rcol) * 68 + rseg * 4];
        s += *(const f32x4*)&buf[(2 * 16 + rcol) * 68 + rseg * 4];
        s += *(const f32x4*)&buf[(3 * 16 + rcol) * 68 + rseg * 4];
        *(f32x4*)&Opart[obase + (size_t)(j * 16 + rcol) * NTOK + qbase + rseg * 4] = s;
        __syncthreads();
    }
}

// ---------------------------------------------------------------------------
// Merge split-K partials. Block = (h, 64 toks). Coalesced reads along tok,
// LDS transpose, coalesced bf16 writes to Ob[tok][dim].
// ---------------------------------------------------------------------------
__global__ __launch_bounds__(256) void k_merge(const float* __restrict__ Opart,
                                               const float* __restrict__ Lpart,
                                               ushort_t* __restrict__ Ob) {
    int h = blockIdx.x / 36, tb = blockIdx.x % 36;
    int tok0 = tb * 64;
    int t = threadIdx.x;
    int tok = t & 63, cbase = t >> 6;      // thread: fixed tok, c = cbase + 4i

    float acc[16];
    #pragma unroll
    for (int i = 0; i < 16; i++) acc[i] = 0.f;
    float l = 0.f;
    for (int ch = 0; ch < CHUNKS; ch++) {
        size_t base = (size_t)(ch * HEADS + h) * HD * NTOK;
        #pragma unroll
        for (int i = 0; i < 16; i++)
            acc[i] += Opart[base + (size_t)(cbase + i * 4) * NTOK + tok0 + tok];
        l += Lpart[(size_t)(ch * HEADS + h) * NTOK + tok0 + tok];
    }
    float inv = 1.0f / l;

    __shared__ ushort_t Tb[64][72];
    #pragma unroll
    for (int i = 0; i < 16; i++)
        Tb[tok][cbase + i * 4] = f2bf(acc[i] * inv);
    __syncthreads();
    #pragma unroll
    for (int i = 0; i < 2; i++) {
        int idx = t + i * 256;             // over 512 uint4 (64 rows x 8)
        int r = idx >> 3, part = idx & 7;
        uint4 val = *(const uint4*)&Tb[r][part * 8];
        *(uint4*)&Ob[(size_t)(tok0 + r) * DIM + h * HD + part * 8] = val;
    }
}

// ---------------------------------------------------------------------------
// Output projection: 128x128 tile, 2x2 waves of 64x64, stride-40 LDS.
// ---------------------------------------------------------------------------
__global__ __launch_bounds__(256) void k_gemm_proj(
    const ushort_t* __restrict__ Ob, const ushort_t* __restrict__ WTp,
    const float* __restrict__ bp, float* __restrict__ out) {
    __shared__ __align__(16) ushort_t As[128 * 40];
    __shared__ __align__(16) ushort_t Bs[128 * 40];
    int tid = threadIdx.x;
    int wave = tid >> 6, lane = tid & 63, quad = lane >> 4, l16 = lane & 15;
    int wx = wave & 1, wy = wave >> 1;
    int nb = blockIdx.x * 128, mb = blockIdx.y * 128;

    f32x4 zero = {0.f, 0.f, 0.f, 0.f};
    f32x4 acc[4][4];
    #pragma unroll
    for (int i = 0; i < 4; i++)
        #pragma unroll
        for (int j = 0; j < 4; j++) acc[i][j] = zero;

    const ushort_t* Ag = Ob + (size_t)(mb + (tid >> 1)) * DIM + (tid & 1) * 16;
    const ushort_t* Bg = WTp + (size_t)(nb + (tid >> 1)) * DIM + (tid & 1) * 16;
    int sidx = (tid >> 1) * 40 + (tid & 1) * 16;

    for (int k0 = 0; k0 < DIM; k0 += 32) {
        uint4 a0 = *(const uint4*)(Ag + k0);
        uint4 a1 = *(const uint4*)(Ag + k0 + 8);
        uint4 b0 = *(const uint4*)(Bg + k0);
        uint4 b1 = *(const uint4*)(Bg + k0 + 8);
        __syncthreads();
        *(uint4*)&As[sidx] = a0;  *(uint4*)&As[sidx + 8] = a1;
        *(uint4*)&Bs[sidx] = b0;  *(uint4*)&Bs[sidx + 8] = b1;
        __syncthreads();
        bf16x8 af[4], bf[4];
        #pragma unroll
        for (int i = 0; i < 4; i++)
            af[i] = *(const bf16x8*)&As[(wy * 64 + i * 16 + l16) * 40 + quad * 8];
        #pragma unroll
        for (int j = 0; j < 4; j++)
            bf[j] = *(const bf16x8*)&Bs[(wx * 64 + j * 16 + l16) * 40 + quad * 8];
        #pragma unroll
        for (int i = 0; i < 4; i++)
            #pragma unroll
            for (int j = 0; j < 4; j++)
                acc[i][j] = __builtin_amdgcn_mfma_f32_16x16x32_bf16(af[i], bf[j], acc[i][j], 0, 0, 0);
    }

    #pragma unroll
    for (int j = 0; j < 4; j++) {
        int col = nb + wx * 64 + j * 16 + l16;
        float bval = bp[col];
        #pragma unroll
        for (int i = 0; i < 4; i++) {
            #pragma unroll
            for (int r = 0; r < 4; r++) {
                int row = mb + wy * 64 + i * 16 + quad * 4 + r;
                out[(size_t)row * DIM + col] = acc[i][j][r] + bval;
            }
        }
    }
}

// ---------------------------------------------------------------------------
extern "C" void kernel_launch(void* const* d_in, const int* in_sizes, int n_in,
                              void* d_out, int out_size, void* d_ws, size_t ws_size,
                              hipStream_t stream) {
    const float* x   = (const float*)d_in[0];
    const float* Wq  = (const float*)d_in[1];
    const float* bq  = (const float*)d_in[2];
    const float* Wk  = (const float*)d_in[3];
    const float* bk  = (const float*)d_in[4];
    const float* Wv  = (const float*)d_in[5];
    const float* bv  = (const float*)d_in[6];
    const float* Wp  = (const float*)d_in[7];
    const float* bp  = (const float*)d_in[8];
    const float* rph = (const float*)d_in[9];
    const float* rpw = (const float*)d_in[10];
    const float* Aq  = (const float*)d_in[11];
    const float* Bq  = (const float*)d_in[12];
    const float* Ak  = (const float*)d_in[13];
    const float* Bk  = (const float*)d_in[14];
    const float* Av  = (const float*)d_in[15];
    const float* Bv  = (const float*)d_in[16];
    float* out = (float*)d_out;

    char* w = (char*)d_ws;
    size_t off = 0;
    auto carve = [&](size_t bytes) {
        char* p = w + off;
        off += (bytes + 255) & ~(size_t)255;
        return p;
    };
    ushort_t* xb    = (ushort_t*)carve((size_t)NTOK * DIM * 2);
    ushort_t* WT    = (ushort_t*)carve((size_t)4 * DIM * DIM * 2);
    ushort_t* Qb    = (ushort_t*)carve((size_t)HEADS * NTOK * HD * 2);
    ushort_t* Kb    = (ushort_t*)carve((size_t)HEADS * NTOK * HD * 2);
    ushort_t* Vtb   = (ushort_t*)carve((size_t)HEADS * HD * NTOK * 2);
    float*    relH  = (float*)carve((size_t)HEADS * NTOK * GRD * 4);
    float*    relW  = (float*)carve((size_t)HEADS * NTOK * GRD * 4);
    ushort_t* Ob    = (ushort_t*)carve((size_t)NTOK * DIM * 2);
    float*    Opart = (float*)carve((size_t)CHUNKS * HEADS * NTOK * HD * 4);
    float*    Lpart = (float*)carve((size_t)CHUNKS * HEADS * NTOK * 4);
    ushort_t* rphb  = (ushort_t*)carve((size_t)(2 * GRD - 1) * HD * 2);
    ushort_t* rpwb  = (ushort_t*)carve((size_t)(2 * GRD - 1) * HD * 2);

    k_convert_x<<<dim3(1728 + 12), dim3(256), 0, stream>>>(x, xb, rph, rpw, rphb, rpwb);
    k_fold<<<dim3(DIM / 32, 4 * DIM / 32), dim3(256), 0, stream>>>(
        Wq, Wk, Wv, Wp, Aq, Bq, Ak, Bk, Av, Bv, WT);
    k_gemm_qkv<<<dim3(18, 18), dim3(256), 0, stream>>>(
        xb, WT, bq, bk, bv, Qb, Kb, Vtb);
    k_relmm<<<dim3(288), dim3(256), 0, stream>>>(
        Qb, rphb, rpwb, relH, relW);
    k_attn<<<dim3(HEADS * CHUNKS, NTOK / 64), dim3(256), 0, stream>>>(
        Qb, Kb, Vtb, relH, relW, Opart, Lpart);
    k_merge<<<dim3(HEADS * 36), dim3(256), 0, stream>>>(
        Opart, Lpart, Ob);
    k_gemm_proj<<<dim3(6, 18), dim3(256), 0, stream>>>(
        Ob, WT + (size_t)3 * DIM * DIM, bp, out);
}

// Round 6
// 213.584 us; speedup vs baseline: 1.1682x; 1.1682x over previous
//
#include <hip/hip_runtime.h>

// ---------------------------------------------------------------------------
// LoRA_Attention: fold LoRA into weights; bf16 MFMA GEMMs; split-K flash
// attention: R3 skeleton (coalesced reg-prefetch LDS staging, q=128/block)
// + S^T compute core (packed uint2 P-stores, b128 PV reads) + stride-68
// bank-audited LDS + XCD-swizzled grid. exp2 softmax, no-max (bounded).
// ---------------------------------------------------------------------------

#define DIM   768
#define HEADS 12
#define HD    64
#define NTOK  2304
#define RANK  8
#define GRD   48
#define CHUNKS 4
#define LOG2E 1.44269504088896f

typedef __attribute__((ext_vector_type(8))) short bf16x8;
typedef __attribute__((ext_vector_type(4))) float f32x4;
typedef unsigned short ushort_t;

__device__ __forceinline__ unsigned short f2bf(float x) {
    union { float f; unsigned u; } v; v.f = x;
    unsigned r = v.u + 0x7fffu + ((v.u >> 16) & 1u);
    return (unsigned short)(r >> 16);
}
__device__ __forceinline__ float bf2f(unsigned short h) {
    return __uint_as_float(((unsigned)h) << 16);
}

__device__ __forceinline__ void gload_lds16(const ushort_t* g, ushort_t* l) {
    __builtin_amdgcn_global_load_lds(
        (const __attribute__((address_space(1))) unsigned int*)g,
        (__attribute__((address_space(3))) unsigned int*)l, 16, 0, 0);
}

// ---------------------------------------------------------------------------
// Stage 0: convert x -> bf16; blocks >= 1728 convert rel_pos tables -> bf16.
// ---------------------------------------------------------------------------
__global__ __launch_bounds__(256) void k_convert_x(
    const float* __restrict__ x, ushort_t* __restrict__ xb,
    const float* __restrict__ rph, const float* __restrict__ rpw,
    ushort_t* __restrict__ rphb, ushort_t* __restrict__ rpwb) {
    if (blockIdx.x < 1728) {
        int idx = (blockIdx.x * 256 + threadIdx.x) * 4;
        float4 v = *(const float4*)(x + idx);
        ushort4 o = make_ushort4(f2bf(v.x), f2bf(v.y), f2bf(v.z), f2bf(v.w));
        *(ushort4*)(xb + idx) = o;
    } else {
        int e = ((blockIdx.x - 1728) * 256 + threadIdx.x) * 4;
        const int TSZ = (2 * GRD - 1) * HD;   // 6080
        if (e < TSZ) {
            float4 v = *(const float4*)(rph + e);
            ushort4 o = make_ushort4(f2bf(v.x), f2bf(v.y), f2bf(v.z), f2bf(v.w));
            *(ushort4*)(rphb + e) = o;
        } else if (e < 2 * TSZ) {
            float4 v = *(const float4*)(rpw + e - TSZ);
            ushort4 o = make_ushort4(f2bf(v.x), f2bf(v.y), f2bf(v.z), f2bf(v.w));
            *(ushort4*)(rpwb + e - TSZ) = o;
        }
    }
}

// ---------------------------------------------------------------------------
__global__ __launch_bounds__(256) void k_fold(
    const float* __restrict__ Wq, const float* __restrict__ Wk,
    const float* __restrict__ Wv, const float* __restrict__ Wp,
    const float* __restrict__ Aq, const float* __restrict__ Bq,
    const float* __restrict__ Ak, const float* __restrict__ Bk,
    const float* __restrict__ Av, const float* __restrict__ Bv,
    ushort_t* __restrict__ WT) {
    int kb = blockIdx.x * 32;
    int nb = blockIdx.y * 32;
    int qkv = nb / DIM;
    int nmod = nb % DIM;
    const float* W = (qkv == 0) ? Wq : (qkv == 1) ? Wk : (qkv == 2) ? Wv : Wp;
    const float* A = (qkv == 0) ? Aq : (qkv == 1) ? Ak : Av;
    const float* B = (qkv == 0) ? Bq : (qkv == 1) ? Bk : Bv;

    __shared__ float T[32][33];
    for (int i = threadIdx.x; i < 1024; i += 256) {
        int kl = i / 32, nl = i % 32;
        float v = W[(kb + kl) * DIM + nmod + nl];
        if (qkv < 3) {
            #pragma unroll
            for (int r = 0; r < RANK; r++)
                v += A[(kb + kl) * RANK + r] * B[r * DIM + nmod + nl];
        }
        T[kl][nl] = v;
    }
    __syncthreads();
    for (int i = threadIdx.x; i < 1024; i += 256) {
        int nl = i / 32, kl = i % 32;
        WT[(size_t)(nb + nl) * DIM + kb + kl] = f2bf(T[kl][nl]);
    }
}

// ---------------------------------------------------------------------------
// QKV GEMM: 128x128 tile, BK=32, global_load_lds width-16 DMA staging.
// ---------------------------------------------------------------------------
__global__ __launch_bounds__(256) void k_gemm_qkv(
    const ushort_t* __restrict__ xb, const ushort_t* __restrict__ WT,
    const float* __restrict__ bq, const float* __restrict__ bk,
    const float* __restrict__ bv,
    ushort_t* __restrict__ Qb, ushort_t* __restrict__ Kb,
    ushort_t* __restrict__ Vtb) {
    __shared__ __align__(16) ushort_t As[128 * 32];
    __shared__ __align__(16) ushort_t Bs[128 * 32];
    int tid = threadIdx.x;
    int wave = tid >> 6, lane = tid & 63, quad = lane >> 4, l16 = lane & 15;
    int wx = wave & 1, wy = wave >> 1;
    int nb = blockIdx.x * 128, mb = blockIdx.y * 128;

    f32x4 zero = {0.f, 0.f, 0.f, 0.f};
    f32x4 acc[4][4];
    #pragma unroll
    for (int i = 0; i < 4; i++)
        #pragma unroll
        for (int j = 0; j < 4; j++) acc[i][j] = zero;

    int rl = lane >> 2;            // 0..15
    int cl = (lane & 3) * 8;       // element col within 32
    const ushort_t* gA = xb + (size_t)(mb + wave * 32 + rl) * DIM + cl;
    const ushort_t* gB = WT + (size_t)(nb + wave * 32 + rl) * DIM + cl;
    ushort_t* lA = &As[(wave * 32) * 32];
    ushort_t* lB = &Bs[(wave * 32) * 32];

    for (int k0 = 0; k0 < DIM; k0 += 32) {
        __syncthreads();
        gload_lds16(gA + k0,            lA);
        gload_lds16(gA + k0 + 16 * DIM, lA + 16 * 32);
        gload_lds16(gB + k0,            lB);
        gload_lds16(gB + k0 + 16 * DIM, lB + 16 * 32);
        __syncthreads();
        bf16x8 af[4], bf[4];
        #pragma unroll
        for (int i = 0; i < 4; i++)
            af[i] = *(const bf16x8*)&As[(wy * 64 + i * 16 + l16) * 32 + quad * 8];
        #pragma unroll
        for (int j = 0; j < 4; j++)
            bf[j] = *(const bf16x8*)&Bs[(wx * 64 + j * 16 + l16) * 32 + quad * 8];
        #pragma unroll
        for (int i = 0; i < 4; i++)
            #pragma unroll
            for (int j = 0; j < 4; j++)
                acc[i][j] = __builtin_amdgcn_mfma_f32_16x16x32_bf16(af[i], bf[j], acc[i][j], 0, 0, 0);
    }

    #pragma unroll
    for (int j = 0; j < 4; j++) {
        int col = nb + wx * 64 + j * 16 + l16;
        int qkv = col / DIM, rem = col % DIM;
        int hh = rem >> 6, cc = rem & 63;
        const float* bias = (qkv == 0) ? bq : (qkv == 1) ? bk : bv;
        float bval = bias[rem];
        #pragma unroll
        for (int i = 0; i < 4; i++) {
            #pragma unroll
            for (int r = 0; r < 4; r++) {
                int row = mb + wy * 64 + i * 16 + quad * 4 + r;
                unsigned short o = f2bf(acc[i][j][r] + bval);
                if (qkv == 0)      Qb[(size_t)(hh * NTOK + row) * HD + cc] = o;
                else if (qkv == 1) Kb[(size_t)(hh * NTOK + row) * HD + cc] = o;
                else               Vtb[(size_t)(hh * HD + cc) * NTOK + row] = o;
            }
        }
    }
}

// ---------------------------------------------------------------------------
// Rel-pos bias via MFMA (outputs pre-scaled by log2 e).
// ---------------------------------------------------------------------------
__global__ __launch_bounds__(256) void k_relmm(
    const ushort_t* __restrict__ Qb, const ushort_t* __restrict__ rphb,
    const ushort_t* __restrict__ rpwb, float* __restrict__ relH,
    float* __restrict__ relW) {
    int id = blockIdx.x * 4 + (threadIdx.x >> 6);
    int lane = threadIdx.x & 63, quad = lane >> 4, l16 = lane & 15;
    bool isW = id >= 576;
    int t = isW ? id - 576 : id;
    int h = t / GRD, g = t % GRD;
    const ushort_t* tab = isW ? rpwb : rphb;
    float* outp = isW ? relW : relH;

    f32x4 zero = {0.f, 0.f, 0.f, 0.f};
    f32x4 acc[3][3];
    #pragma unroll
    for (int i = 0; i < 3; i++)
        #pragma unroll
        for (int j = 0; j < 3; j++) acc[i][j] = zero;

    bf16x8 bfr[3][2];
    #pragma unroll
    for (int ct = 0; ct < 3; ct++) {
        int trow = g + 47 - (ct * 16 + l16);
        bfr[ct][0] = *(const bf16x8*)&tab[(size_t)trow * HD + quad * 8];
        bfr[ct][1] = *(const bf16x8*)&tab[(size_t)trow * HD + 32 + quad * 8];
    }
    #pragma unroll
    for (int ms = 0; ms < 3; ms++) {
        int m = ms * 16 + l16;
        int n = isW ? m * GRD + g : g * GRD + m;
        bf16x8 a0 = *(const bf16x8*)&Qb[(size_t)(h * NTOK + n) * HD + quad * 8];
        bf16x8 a1 = *(const bf16x8*)&Qb[(size_t)(h * NTOK + n) * HD + 32 + quad * 8];
        #pragma unroll
        for (int ct = 0; ct < 3; ct++) {
            acc[ms][ct] = __builtin_amdgcn_mfma_f32_16x16x32_bf16(a0, bfr[ct][0], acc[ms][ct], 0, 0, 0);
            acc[ms][ct] = __builtin_amdgcn_mfma_f32_16x16x32_bf16(a1, bfr[ct][1], acc[ms][ct], 0, 0, 0);
        }
    }
    #pragma unroll
    for (int ms = 0; ms < 3; ms++) {
        #pragma unroll
        for (int ct = 0; ct < 3; ct++) {
            #pragma unroll
            for (int r = 0; r < 4; r++) {
                int m = ms * 16 + quad * 4 + r;
                int n = isW ? m * GRD + g : g * GRD + m;
                int col = ct * 16 + l16;
                outp[(size_t)(h * NTOK + n) * GRD + col] = acc[ms][ct][r] * LOG2E;
            }
        }
    }
}

// ---------------------------------------------------------------------------
// Flash attention, split-K. Block = (128 q-rows, head, chunk of 576 keys).
// Grid x = h*4+chunk (48 = 0 mod 8 stride -> XCD-local K/V sharing).
// R3-style staging: coalesced uint4 reg-prefetch -> LDS (stride 68: dword
// stride 34 = 2 mod 32, uniform banks for b128). S^T QK (D[m=key][n=qrow]):
// P packs in-lane to uint2, PV A-frag is one b128. Wave owns 32 q-rows
// (2 strips) -> l and O complete per-wave, no cross-wave reduction.
// ---------------------------------------------------------------------------
__global__ __launch_bounds__(256) void k_attn(
    const ushort_t* __restrict__ Qb, const ushort_t* __restrict__ Kb,
    const ushort_t* __restrict__ Vtb, const float* __restrict__ relH,
    const float* __restrict__ relW, float* __restrict__ Opart,
    float* __restrict__ Lpart) {
    int h = blockIdx.x >> 2, chunk = blockIdx.x & 3, qt = blockIdx.y;
    int tid = threadIdx.x;
    int wave = tid >> 6, lane = tid & 63, quad = lane >> 4, l16 = lane & 15;
    int qbase = qt * 128;
    int kbase = chunk * 576;

    __shared__ __align__(16) ushort_t Ks[64 * 68];      // K tile [key][c]
    __shared__ __align__(16) ushort_t Vs[64 * 68];      // V^T tile [c][key]
    __shared__ __align__(16) ushort_t Ps[4][32 * 68];   // per-wave P [qrow][key]
    __shared__ __align__(16) ushort_t rws[128 * 52];    // bf16 relW [qrow][48]
    __shared__ __align__(16) ushort_t rhs[128 * 14];    // bf16 relH [qrow][12]

    // stage rel terms (pre-scaled by log2e in k_relmm), bf16
    for (int i = tid; i < 128 * 48; i += 256) {
        int r = i / 48, c = i % 48;
        rws[r * 52 + c] = f2bf(relW[(size_t)(h * NTOK + qbase + r) * GRD + c]);
    }
    for (int i = tid; i < 128 * 12; i += 256) {
        int r = i / 12, c = i % 12;
        rhs[r * 14 + c] = f2bf(relH[(size_t)(h * NTOK + qbase + r) * GRD + chunk * 12 + c]);
    }

    // Q B-fragments (B[k=c][n=qrow], n=l16); wave owns rows wave*32..+31
    bf16x8 qf[2][2];
    #pragma unroll
    for (int s = 0; s < 2; s++) {
        int qrow = qbase + wave * 32 + s * 16 + l16;
        qf[s][0] = *(const bf16x8*)&Qb[(size_t)(h * NTOK + qrow) * HD + quad * 8];
        qf[s][1] = *(const bf16x8*)&Qb[(size_t)(h * NTOK + qrow) * HD + 32 + quad * 8];
    }

    // staging addresses: thread covers K chunks {tid, tid+256}, V likewise.
    // chunk idx: row = idx>>3, col16 = (idx&7)*8
    int r0 = tid >> 3, c0 = (tid & 7) * 8;
    const ushort_t* kg0 = Kb + (size_t)(h * NTOK + r0) * HD + c0;          // + kb*HD
    const ushort_t* kg1 = Kb + (size_t)(h * NTOK + r0 + 32) * HD + c0;
    const ushort_t* vg0 = Vtb + (size_t)(h * HD + r0) * NTOK + c0;         // + kb
    const ushort_t* vg1 = Vtb + (size_t)(h * HD + r0 + 32) * NTOK + c0;
    int sk0 = r0 * 68 + c0, sk1 = sk0 + 32 * 68;

    float lacc[2] = {0.f, 0.f};
    f32x4 zero = {0.f, 0.f, 0.f, 0.f};
    f32x4 oacc[2][4];
    #pragma unroll
    for (int s = 0; s < 2; s++)
        #pragma unroll
        for (int cs = 0; cs < 4; cs++) oacc[s][cs] = zero;

    const float scale2 = 0.125f * LOG2E;

    // prefetch tile 0
    uint4 rk0 = *(const uint4*)(kg0 + (size_t)kbase * HD);
    uint4 rk1 = *(const uint4*)(kg1 + (size_t)kbase * HD);
    uint4 rv0 = *(const uint4*)(vg0 + kbase);
    uint4 rv1 = *(const uint4*)(vg1 + kbase);

    for (int kt = 0; kt < 9; kt++) {
        int kb = kbase + kt * 64;
        __syncthreads();                 // all waves done reading prev K/V tile
        *(uint4*)&Ks[sk0] = rk0;  *(uint4*)&Ks[sk1] = rk1;
        *(uint4*)&Vs[sk0] = rv0;  *(uint4*)&Vs[sk1] = rv1;
        __syncthreads();
        if (kt < 8) {                    // issue next tile's loads
            int kbn = kb + 64;
            rk0 = *(const uint4*)(kg0 + (size_t)kbn * HD);
            rk1 = *(const uint4*)(kg1 + (size_t)kbn * HD);
            rv0 = *(const uint4*)(vg0 + kbn);
            rv1 = *(const uint4*)(vg1 + kbn);
        }

        // QK^T (S^T: D[m=key][n=qrow]) + softmax + packed P store, per 16-key grp
        #pragma unroll
        for (int ks = 0; ks < 4; ks++) {
            bf16x8 kf0 = *(const bf16x8*)&Ks[(ks * 16 + l16) * 68 + quad * 8];
            bf16x8 kf1 = *(const bf16x8*)&Ks[(ks * 16 + l16) * 68 + 32 + quad * 8];
            f32x4 st[2];
            #pragma unroll
            for (int s = 0; s < 2; s++) {
                f32x4 z = zero;
                z = __builtin_amdgcn_mfma_f32_16x16x32_bf16(kf0, qf[s][0], z, 0, 0, 0);
                z = __builtin_amdgcn_mfma_f32_16x16x32_bf16(kf1, qf[s][1], z, 0, 0, 0);
                st[s] = z;
            }
            int kb4 = kb + ks * 16 + quad * 4;     // lane's first key (4-aligned)
            int kh = kb4 / 48;
            int khl = kh - chunk * 12;
            int kw0 = kb4 - kh * 48;
            #pragma unroll
            for (int s = 0; s < 2; s++) {
                int row = wave * 32 + s * 16 + l16;    // block-local qrow
                float rh = bf2f(rhs[row * 14 + khl]);
                uint2 u = *(const uint2*)&rws[row * 52 + kw0];
                float p0 = __builtin_amdgcn_exp2f(st[s][0] * scale2 + rh + __uint_as_float(u.x << 16));
                float p1 = __builtin_amdgcn_exp2f(st[s][1] * scale2 + rh + __uint_as_float(u.x & 0xffff0000u));
                float p2 = __builtin_amdgcn_exp2f(st[s][2] * scale2 + rh + __uint_as_float(u.y << 16));
                float p3 = __builtin_amdgcn_exp2f(st[s][3] * scale2 + rh + __uint_as_float(u.y & 0xffff0000u));
                lacc[s] += (p0 + p1) + (p2 + p3);
                uint2 w;
                w.x = __builtin_amdgcn_perm(__float_as_uint(p1), __float_as_uint(p0), 0x07060302u);
                w.y = __builtin_amdgcn_perm(__float_as_uint(p3), __float_as_uint(p2), 0x07060302u);
                *(uint2*)&Ps[wave][(s * 16 + l16) * 68 + ks * 16 + quad * 4] = w;
            }
        }

        // PV: A[m=qrow][k=key] b128 from own Ps; B[k=key][n=c] b128 from Vs
        bf16x8 vf[4][2];
        #pragma unroll
        for (int cs = 0; cs < 4; cs++) {
            vf[cs][0] = *(const bf16x8*)&Vs[(cs * 16 + l16) * 68 + quad * 8];
            vf[cs][1] = *(const bf16x8*)&Vs[(cs * 16 + l16) * 68 + 32 + quad * 8];
        }
        #pragma unroll
        for (int s = 0; s < 2; s++) {
            bf16x8 pa0 = *(const bf16x8*)&Ps[wave][(s * 16 + l16) * 68 + quad * 8];
            bf16x8 pa1 = *(const bf16x8*)&Ps[wave][(s * 16 + l16) * 68 + 32 + quad * 8];
            #pragma unroll
            for (int cs = 0; cs < 4; cs++) {
                oacc[s][cs] = __builtin_amdgcn_mfma_f32_16x16x32_bf16(pa0, vf[cs][0], oacc[s][cs], 0, 0, 0);
                oacc[s][cs] = __builtin_amdgcn_mfma_f32_16x16x32_bf16(pa1, vf[cs][1], oacc[s][cs], 0, 0, 0);
            }
        }
    }

    // l: reduce over quads (keys split across quads)
    #pragma unroll
    for (int s = 0; s < 2; s++) {
        float l = lacc[s];
        l += __shfl_xor(l, 16);
        l += __shfl_xor(l, 32);
        lacc[s] = l;
    }

    // write partials: Opart [chunk][h][tok][c] (coalesced), Lpart [chunk][h][tok]
    size_t obase = (size_t)(chunk * HEADS + h) * NTOK;
    #pragma unroll
    for (int s = 0; s < 2; s++) {
        #pragma unroll
        for (int cs = 0; cs < 4; cs++) {
            #pragma unroll
            for (int r = 0; r < 4; r++) {
                int row = qbase + wave * 32 + s * 16 + quad * 4 + r;
                Opart[(obase + row) * HD + cs * 16 + l16] = oacc[s][cs][r];
            }
        }
        if (quad == 0)
            Lpart[obase + qbase + wave * 32 + s * 16 + l16] = lacc[s];
    }
}

// ---------------------------------------------------------------------------
// Merge split-K partials: Ob = (sum_ch O) / (sum_ch l), bf16.
// ---------------------------------------------------------------------------
__global__ __launch_bounds__(256) void k_merge(const float* __restrict__ Opart,
                                               const float* __restrict__ Lpart,
                                               ushort_t* __restrict__ Ob) {
    int t = blockIdx.x * 256 + threadIdx.x;
    int e = t * 4;                       // flat over [h][row][c]
    int c = e & (HD - 1);
    int row = (e >> 6) % NTOK;
    int h = e / (NTOK * HD);
    const int ostride = HEADS * NTOK * HD;
    float4 s = {0.f, 0.f, 0.f, 0.f};
    float l = 0.f;
    #pragma unroll
    for (int ch = 0; ch < CHUNKS; ch++) {
        float4 v = *(const float4*)&Opart[(size_t)ch * ostride + e];
        s.x += v.x; s.y += v.y; s.z += v.z; s.w += v.w;
        l += Lpart[(size_t)(ch * HEADS + h) * NTOK + row];
    }
    float inv = 1.0f / l;
    ushort4 o = make_ushort4(f2bf(s.x * inv), f2bf(s.y * inv),
                             f2bf(s.z * inv), f2bf(s.w * inv));
    *(ushort4*)&Ob[(size_t)row * DIM + h * HD + c] = o;
}

// ---------------------------------------------------------------------------
// Output projection: 128x128 tile, 2x2 waves of 64x64, stride-40 LDS.
// ---------------------------------------------------------------------------
__global__ __launch_bounds__(256) void k_gemm_proj(
    const ushort_t* __restrict__ Ob, const ushort_t* __restrict__ WTp,
    const float* __restrict__ bp, float* __restrict__ out) {
    __shared__ __align__(16) ushort_t As[128 * 40];
    __shared__ __align__(16) ushort_t Bs[128 * 40];
    int tid = threadIdx.x;
    int wave = tid >> 6, lane = tid & 63, quad = lane >> 4, l16 = lane & 15;
    int wx = wave & 1, wy = wave >> 1;
    int nb = blockIdx.x * 128, mb = blockIdx.y * 128;

    f32x4 zero = {0.f, 0.f, 0.f, 0.f};
    f32x4 acc[4][4];
    #pragma unroll
    for (int i = 0; i < 4; i++)
        #pragma unroll
        for (int j = 0; j < 4; j++) acc[i][j] = zero;

    const ushort_t* Ag = Ob + (size_t)(mb + (tid >> 1)) * DIM + (tid & 1) * 16;
    const ushort_t* Bg = WTp + (size_t)(nb + (tid >> 1)) * DIM + (tid & 1) * 16;
    int sidx = (tid >> 1) * 40 + (tid & 1) * 16;

    for (int k0 = 0; k0 < DIM; k0 += 32) {
        uint4 a0 = *(const uint4*)(Ag + k0);
        uint4 a1 = *(const uint4*)(Ag + k0 + 8);
        uint4 b0 = *(const uint4*)(Bg + k0);
        uint4 b1 = *(const uint4*)(Bg + k0 + 8);
        __syncthreads();
        *(uint4*)&As[sidx] = a0;  *(uint4*)&As[sidx + 8] = a1;
        *(uint4*)&Bs[sidx] = b0;  *(uint4*)&Bs[sidx + 8] = b1;
        __syncthreads();
        bf16x8 af[4], bf[4];
        #pragma unroll
        for (int i = 0; i < 4; i++)
            af[i] = *(const bf16x8*)&As[(wy * 64 + i * 16 + l16) * 40 + quad * 8];
        #pragma unroll
        for (int j = 0; j < 4; j++)
            bf[j] = *(const bf16x8*)&Bs[(wx * 64 + j * 16 + l16) * 40 + quad * 8];
        #pragma unroll
        for (int i = 0; i < 4; i++)
            #pragma unroll
            for (int j = 0; j < 4; j++)
                acc[i][j] = __builtin_amdgcn_mfma_f32_16x16x32_bf16(af[i], bf[j], acc[i][j], 0, 0, 0);
    }

    #pragma unroll
    for (int j = 0; j < 4; j++) {
        int col = nb + wx * 64 + j * 16 + l16;
        float bval = bp[col];
        #pragma unroll
        for (int i = 0; i < 4; i++) {
            #pragma unroll
            for (int r = 0; r < 4; r++) {
                int row = mb + wy * 64 + i * 16 + quad * 4 + r;
                out[(size_t)row * DIM + col] = acc[i][j][r] + bval;
            }
        }
    }
}

// ---------------------------------------------------------------------------
extern "C" void kernel_launch(void* const* d_in, const int* in_sizes, int n_in,
                              void* d_out, int out_size, void* d_ws, size_t ws_size,
                              hipStream_t stream) {
    const float* x   = (const float*)d_in[0];
    const float* Wq  = (const float*)d_in[1];
    const float* bq  = (const float*)d_in[2];
    const float* Wk  = (const float*)d_in[3];
    const float* bk  = (const float*)d_in[4];
    const float* Wv  = (const float*)d_in[5];
    const float* bv  = (const float*)d_in[6];
    const float* Wp  = (const float*)d_in[7];
    const float* bp  = (const float*)d_in[8];
    const float* rph = (const float*)d_in[9];
    const float* rpw = (const float*)d_in[10];
    const float* Aq  = (const float*)d_in[11];
    const float* Bq  = (const float*)d_in[12];
    const float* Ak  = (const float*)d_in[13];
    const float* Bk  = (const float*)d_in[14];
    const float* Av  = (const float*)d_in[15];
    const float* Bv  = (const float*)d_in[16];
    float* out = (float*)d_out;

    char* w = (char*)d_ws;
    size_t off = 0;
    auto carve = [&](size_t bytes) {
        char* p = w + off;
        off += (bytes + 255) & ~(size_t)255;
        return p;
    };
    ushort_t* xb    = (ushort_t*)carve((size_t)NTOK * DIM * 2);
    ushort_t* WT    = (ushort_t*)carve((size_t)4 * DIM * DIM * 2);
    ushort_t* Qb    = (ushort_t*)carve((size_t)HEADS * NTOK * HD * 2);
    ushort_t* Kb    = (ushort_t*)carve((size_t)HEADS * NTOK * HD * 2);
    ushort_t* Vtb   = (ushort_t*)carve((size_t)HEADS * HD * NTOK * 2);
    float*    relH  = (float*)carve((size_t)HEADS * NTOK * GRD * 4);
    float*    relW  = (float*)carve((size_t)HEADS * NTOK * GRD * 4);
    ushort_t* Ob    = (ushort_t*)carve((size_t)NTOK * DIM * 2);
    float*    Opart = (float*)carve((size_t)CHUNKS * HEADS * NTOK * HD * 4);
    float*    Lpart = (float*)carve((size_t)CHUNKS * HEADS * NTOK * 4);
    ushort_t* rphb  = (ushort_t*)carve((size_t)(2 * GRD - 1) * HD * 2);
    ushort_t* rpwb  = (ushort_t*)carve((size_t)(2 * GRD - 1) * HD * 2);

    k_convert_x<<<dim3(1728 + 12), dim3(256), 0, stream>>>(x, xb, rph, rpw, rphb, rpwb);
    k_fold<<<dim3(DIM / 32, 4 * DIM / 32), dim3(256), 0, stream>>>(
        Wq, Wk, Wv, Wp, Aq, Bq, Ak, Bk, Av, Bv, WT);
    k_gemm_qkv<<<dim3(18, 18), dim3(256), 0, stream>>>(
        xb, WT, bq, bk, bv, Qb, Kb, Vtb);
    k_relmm<<<dim3(288), dim3(256), 0, stream>>>(
        Qb, rphb, rpwb, relH, relW);
    k_attn<<<dim3(HEADS * CHUNKS, NTOK / 128), dim3(256), 0, stream>>>(
        Qb, Kb, Vtb, relH, relW, Opart, Lpart);
    k_merge<<<dim3(HEADS * NTOK * HD / (256 * 4)), dim3(256), 0, stream>>>(
        Opart, Lpart, Ob);
    k_gemm_proj<<<dim3(6, 18), dim3(256), 0, stream>>>(
        Ob, WT + (size_t)3 * DIM * DIM, bp, out);
}